// Round 2
// baseline (180.444 us; speedup 1.0000x reference)
//
#include <hip/hip_runtime.h>

// Problem: B=64, H=W=512 fp32. out = x + (f - conv3x3(x,k_b)) / 6, zero pad,
// cross-correlation (no kernel flip).
#define BB 64
#define HH 512
#define WW 512
#define P  8   // output rows per wave strip

// One wave (64 lanes) covers a full 512-wide row: lane l owns floats
// [8l, 8l+8). It marches P consecutive rows with a sliding 3-row register
// window, so each x row is loaded once per wave.

struct Ext { float e[10]; };  // [left halo, 8 owned floats, right halo]

__device__ __forceinline__ Ext load_ext_row(const float* __restrict__ xrow,
                                            int c0, int lane) {
    Ext r;
    const float4 q0 = *(const float4*)(xrow + c0);
    const float4 q1 = *(const float4*)(xrow + c0 + 4);
    r.e[1] = q0.x; r.e[2] = q0.y; r.e[3] = q0.z; r.e[4] = q0.w;
    r.e[5] = q1.x; r.e[6] = q1.y; r.e[7] = q1.z; r.e[8] = q1.w;
    r.e[0] = (lane > 0)  ? xrow[c0 - 1] : 0.f;   // left halo (0 at j edge)
    r.e[9] = (lane < 63) ? xrow[c0 + 8] : 0.f;   // right halo
    return r;
}

__device__ __forceinline__ Ext zero_ext() {
    Ext r;
#pragma unroll
    for (int j = 0; j < 10; ++j) r.e[j] = 0.f;
    return r;
}

__global__ __launch_bounds__(256) void jacobi_march_kernel(
    const float* __restrict__ x,
    const float* __restrict__ f,
    const float* __restrict__ k,
    float* __restrict__ out)
{
    const int lane = threadIdx.x & 63;
    const int wv   = threadIdx.x >> 6;

    // strip id: wave-uniform by construction; readfirstlane makes it provably
    // scalar so kernel weights compile to s_load and row bases to SGPR math.
    int S = blockIdx.x * 4 + wv;
    S = __builtin_amdgcn_readfirstlane(S);
    const int g  = S & 63;       // row-group within image (64 groups of P=8)
    const int b  = S >> 6;       // batch index
    const int r0 = g * P;
    const int c0 = lane << 3;    // first owned column

    const size_t img = (size_t)b * HH * WW;
    const float* xb = x + img;
    const float* fb = f + img;
    float*       ob = out + img;

    const float* kb = k + b * 9; // b scalar -> s_load_dwordx8 + s_load_dword
    const float k00 = kb[0], k01 = kb[1], k02 = kb[2];
    const float k10 = kb[3], k11 = kb[4], k12 = kb[5];
    const float k20 = kb[6], k21 = kb[7], k22 = kb[8];

    Ext m, c, p;
    m = (r0 > 0) ? load_ext_row(xb + (size_t)(r0 - 1) * WW, c0, lane)
                 : zero_ext();
    c = load_ext_row(xb + (size_t)r0 * WW, c0, lane);

    const float inv6 = 1.f / 6.f;

#pragma unroll
    for (int ii = 0; ii < P; ++ii) {
        const int i = r0 + ii;
        // bottom row of the window (zero row below the image; wave-uniform)
        p = (i + 1 < HH) ? load_ext_row(xb + (size_t)(i + 1) * WW, c0, lane)
                         : zero_ext();

        const float* frow = fb + (size_t)i * WW + c0;
        const float4 f0 = *(const float4*)(frow);
        const float4 f1 = *(const float4*)(frow + 4);

        float o[8];
#pragma unroll
        for (int j = 0; j < 8; ++j) {
            // cross-correlation: k[r][cc] * x[i+r-1][col+cc-1]
            float acc = k00 * m.e[j] + k01 * m.e[j + 1] + k02 * m.e[j + 2]
                      + k10 * c.e[j] + k11 * c.e[j + 1] + k12 * c.e[j + 2]
                      + k20 * p.e[j] + k21 * p.e[j + 1] + k22 * p.e[j + 2];
            // center value x[i][col] = c.e[j+1]
            const float fv = (j < 4) ? ((const float*)&f0)[j]
                                     : ((const float*)&f1)[j - 4];
            o[j] = c.e[j + 1] + (fv - acc) * inv6;
        }

        float* orow = ob + (size_t)i * WW + c0;
        float4 o0 = make_float4(o[0], o[1], o[2], o[3]);
        float4 o1 = make_float4(o[4], o[5], o[6], o[7]);
        *(float4*)(orow)     = o0;
        *(float4*)(orow + 4) = o1;

        m = c;
        c = p;
    }
}

extern "C" void kernel_launch(void* const* d_in, const int* in_sizes, int n_in,
                              void* d_out, int out_size, void* d_ws, size_t ws_size,
                              hipStream_t stream) {
    const float* x = (const float*)d_in[0];
    const float* f = (const float*)d_in[1];
    const float* k = (const float*)d_in[2];
    float* out = (float*)d_out;

    // 64 images * 64 row-groups = 4096 wave-strips; 4 waves per 256-block.
    const int blocks = (BB * (HH / P)) / 4;  // 1024
    jacobi_march_kernel<<<blocks, 256, 0, stream>>>(x, f, k, out);
}